// Round 3
// baseline (329.018 us; speedup 1.0000x reference)
//
#include <hip/hip_runtime.h>
#include <stdint.h>

typedef unsigned short ushort_t;
typedef __attribute__((ext_vector_type(8))) short bf16x8;   // 8 bf16 in 4 VGPRs
typedef __attribute__((ext_vector_type(4))) float f32x4;
typedef __attribute__((ext_vector_type(2))) float f32x2;

#define BKT_SHIFT 7
#define BKT_W     128
#define NB_MAX    1024
#define KB_ITERS  16
#define KB_CHUNK  (256 * KB_ITERS)   // 4096 edges per block
#define BCAP      2560               // lambda=2048, +11 sigma; NB*BCAP*4 = 8.0MB
#define PSLICES   8

// ---------------- helpers ----------------

__device__ __forceinline__ ushort_t f2bf(float f) {
    union { float f; uint32_t u; } a; a.f = f;
    uint32_t u = a.u;
    uint32_t r = (u + 0x7FFFu + ((u >> 16) & 1u)) >> 16;
    return (ushort_t)r;
}
__device__ __forceinline__ float bf_lo(uint32_t p) { return __uint_as_float(p << 16); }
__device__ __forceinline__ float bf_hi(uint32_t p) { return __uint_as_float(p & 0xFFFF0000u); }

// exclusive scan of cnts[0..NB) (NB<=1024) into bb[0..NB]; 256 threads, 4 items each.
__device__ __forceinline__ void bucket_scan(const int* __restrict__ cnts, int NB,
                                            int* pr, int* bb) {
    int t = threadIdx.x;
    int h[4];
    int sum = 0;
#pragma unroll
    for (int j = 0; j < 4; j++) {
        int idx = 4 * t + j;
        h[j] = (idx < NB) ? cnts[idx] : 0;
        sum += h[j];
    }
    pr[t] = sum;
    __syncthreads();
    for (int off = 1; off < 256; off <<= 1) {
        int x = (t >= off) ? pr[t - off] : 0;
        __syncthreads();
        pr[t] += x;
        __syncthreads();
    }
    int ex = pr[t] - sum;
#pragma unroll
    for (int j = 0; j < 4; j++) { bb[4 * t + j] = ex; ex += h[j]; }
    if (t == 255) bb[NB_MAX] = ex;
    __syncthreads();
}

// ---------------- kW_init: weight convert + zero small state ----------------
__global__ __launch_bounds__(256) void kW_init(const float* __restrict__ W1,
                                               const float* __restrict__ W2,
                                               ushort_t* __restrict__ Wt1,
                                               ushort_t* __restrict__ Wt2,
                                               int* __restrict__ bcnt,
                                               float* __restrict__ pooled,   // PSLICES*128
                                               int* __restrict__ counter) {
    int b = blockIdx.x, t = threadIdx.x;
    if (b < 64) {
        int i = b * 256 + t;
        int k = i >> 7, nn = i & 127;
        Wt1[nn * 128 + k] = f2bf(W1[i]);
        Wt2[nn * 128 + k] = f2bf(W2[i]);
    } else {
        for (int i = t; i < NB_MAX; i += 256) bcnt[i] = 0;
        for (int i = t; i < PSLICES * 128; i += 256) pooled[i] = 0.f;
        if (t == 0) *counter = 0;
    }
}

// ---------------- kB_bucket: single-pass scatter into fixed-stride buckets ----------------
// bucket b occupies bpack[b*BCAP .. b*BCAP + bcnt[b]).  pack = (src<<7)|(dst&127)
__global__ __launch_bounds__(256) void kB_bucket(const int* __restrict__ src,
                                                 const int* __restrict__ dst, int E, int NB,
                                                 int* __restrict__ bcnt,
                                                 uint32_t* __restrict__ bpack) {
    __shared__ int lh[NB_MAX];
    int t = threadIdx.x;
    for (int i = t; i < NB; i += 256) lh[i] = 0;
    __syncthreads();

    int base = blockIdx.x * KB_CHUNK;
    int dreg[KB_ITERS], rank[KB_ITERS];
#pragma unroll
    for (int i = 0; i < KB_ITERS; i++) {
        int e = base + t + i * 256;
        if (e < E) {
            int d = dst[e];
            dreg[i] = d;
            rank[i] = atomicAdd(&lh[d >> BKT_SHIFT], 1);
        } else {
            dreg[i] = -1; rank[i] = 0;
        }
    }
    __syncthreads();
    // reserve a contiguous range per touched bucket (global cursor, no prescan)
    for (int i = t; i < NB; i += 256) {
        int c = lh[i];
        lh[i] = c ? atomicAdd(&bcnt[i], c) : 0;
    }
    __syncthreads();
#pragma unroll
    for (int i = 0; i < KB_ITERS; i++) {
        int e = base + t + i * 256;
        if (dreg[i] >= 0) {
            int d = dreg[i];
            int bkt = d >> BKT_SHIFT;
            size_t pos = (size_t)bkt * BCAP + lh[bkt] + rank[i];
            bpack[pos] = ((uint32_t)src[e] << BKT_SHIFT) | (uint32_t)(d & (BKT_W - 1));
        }
    }
}

// ---------------- kC_csr: per-bucket CSR build (no GEMM; 782 blocks) ----------------
__global__ __launch_bounds__(256) void kC_csr(const uint32_t* __restrict__ bpack,
                                              const int* __restrict__ bcnt, int NB, int n,
                                              float* __restrict__ dinv,
                                              int* __restrict__ offs,
                                              int* __restrict__ csr) {
    __shared__ int pr[256];
    __shared__ int bb[NB_MAX + 1];
    __shared__ int cnt[BKT_W];
    __shared__ int cur[BKT_W];

    const int t = threadIdx.x;
    const int b = blockIdx.x;
    bucket_scan(bcnt, NB, pr, bb);
    const int nb0 = b << BKT_SHIFT;
    const int wlen = min(BKT_W, n - nb0);
    const int e0 = bb[b];                 // csr base for this bucket
    const int cntb = bb[b + 1] - e0;      // edges in this bucket
    const uint32_t* bp = bpack + (size_t)b * BCAP;

    if (t < BKT_W) cnt[t] = 0;
    __syncthreads();
    for (int e = t; e < cntb; e += 256)
        atomicAdd(&cnt[bp[e] & (BKT_W - 1)], 1);
    __syncthreads();

    // scan cnt[0..BKT_W) with first BKT_W threads (pr reused; barriers full-block)
    int v = (t < BKT_W) ? cnt[t] : 0;
    if (t < BKT_W) pr[t] = v;
    __syncthreads();
    for (int off = 1; off < BKT_W; off <<= 1) {
        int x = (t >= off && t < BKT_W) ? pr[t - off] : 0;
        __syncthreads();
        if (t < BKT_W) pr[t] += x;
        __syncthreads();
    }
    if (t < BKT_W) {
        int myoff = e0 + pr[t] - v;
        cur[t] = myoff;
        if (t < wlen) {
            offs[nb0 + t] = myoff;
            dinv[nb0 + t] = rsqrtf((float)(v + 1));
        }
    }
    if (b == NB - 1 && t == 0) offs[n] = bb[NB];
    __syncthreads();

    for (int e = t; e < cntb; e += 256) {
        uint32_t p = bp[e];
        int pos = atomicAdd(&cur[p & (BKT_W - 1)], 1);
        csr[pos] = (int)(p >> BKT_SHIFT);
    }
}

// ---------------- k_gemm1: layer-1 GEMM, f32 in (x), fp8 out (xw1), dinv-scaled ----------------
__global__ __launch_bounds__(256) void k_gemm1(const float* __restrict__ x,
                                               const ushort_t* __restrict__ Wt,
                                               const float* __restrict__ dinv,
                                               uint8_t* __restrict__ C, int n) {
    __shared__ ushort_t al[64 * 136];
    __shared__ ushort_t wl[128 * 136];
    const int t = threadIdx.x;
    const int l = t & 63;
    const int wave = t >> 6;
    const int lane15 = l & 15;
    const int quad = l >> 4;
    const int m0 = blockIdx.x * 64;
    const int rows = min(64, n - m0);

#pragma unroll
    for (int i = 0; i < 8; i++) {
        int f = t + 256 * i;
        int r = f >> 4, c = f & 15;
        *(uint4*)(&wl[r * 136 + c * 8]) = ((const uint4*)Wt)[f];
    }
    {
        const float4* Ap = (const float4*)(x + (size_t)m0 * 128);
        int nf = rows * 32;
#pragma unroll
        for (int i = 0; i < 8; i++) {
            int f = t + 256 * i;
            float4 vv = make_float4(0.f, 0.f, 0.f, 0.f);
            if (f < nf) vv = Ap[f];
            ushort4 us;
            us.x = f2bf(vv.x); us.y = f2bf(vv.y); us.z = f2bf(vv.z); us.w = f2bf(vv.w);
            int r = f >> 5, c = f & 31;
            *(ushort4*)(&al[r * 136 + c * 4]) = us;
        }
    }
    __syncthreads();

    f32x4 acc[8];
#pragma unroll
    for (int nt = 0; nt < 8; nt++) acc[nt] = (f32x4){0.f, 0.f, 0.f, 0.f};

    const int arow = wave * 16 + lane15;
#pragma unroll
    for (int kt = 0; kt < 4; kt++) {
        bf16x8 af = *(const bf16x8*)(&al[arow * 136 + kt * 32 + quad * 8]);
#pragma unroll
        for (int nt = 0; nt < 8; nt++) {
            bf16x8 bfr = *(const bf16x8*)(&wl[(nt * 16 + lane15) * 136 + kt * 32 + quad * 8]);
            acc[nt] = __builtin_amdgcn_mfma_f32_16x16x32_bf16(af, bfr, acc[nt], 0, 0, 0);
        }
    }

    const int rbase = m0 + wave * 16 + quad * 4;
    float dsc[4];
#pragma unroll
    for (int r = 0; r < 4; r++)
        dsc[r] = (rbase + r < n) ? dinv[rbase + r] : 0.f;
#pragma unroll
    for (int nt = 0; nt < 8; nt++) {
        int c0 = nt * 16 + lane15;
#pragma unroll
        for (int r = 0; r < 4; r += 2) {
            int pk = __builtin_amdgcn_cvt_pk_fp8_f32(acc[nt][r] * dsc[r],
                                                     acc[nt][r + 1] * dsc[r + 1], 0, false);
            int row0 = rbase + r, row1 = rbase + r + 1;
            if (row0 < n) C[(size_t)row0 * 128 + c0] = (uint8_t)pk;
            if (row1 < n) C[(size_t)row1 * 128 + c0] = (uint8_t)(pk >> 8);
        }
    }
}

// ---------------- MFMA GEMM (layer 2): bf16 in (h), fp8 out (xw2), dinv-scaled ----------------
__global__ __launch_bounds__(256) void k_gemm_mfma(const ushort_t* __restrict__ A,
                                                   const ushort_t* __restrict__ Wt,
                                                   const float* __restrict__ dinv,
                                                   uint8_t* __restrict__ C, int n) {
    __shared__ ushort_t al[64 * 136];
    __shared__ ushort_t wl[128 * 136];
    const int t = threadIdx.x;
    const int l = t & 63;
    const int wave = t >> 6;
    const int lane15 = l & 15;
    const int quad = l >> 4;
    const int m0 = blockIdx.x * 64;
    const int rows = min(64, n - m0);

#pragma unroll
    for (int i = 0; i < 8; i++) {
        int f = t + 256 * i;
        int r = f >> 4, c = f & 15;
        *(uint4*)(&wl[r * 136 + c * 8]) = ((const uint4*)Wt)[f];
    }
    {
        const uint4* Ap = (const uint4*)(A + (size_t)m0 * 128);
        int nf = rows * 16;
#pragma unroll
        for (int i = 0; i < 4; i++) {
            int f = t + 256 * i;
            uint4 v = make_uint4(0, 0, 0, 0);
            if (f < nf) v = Ap[f];
            int r = f >> 4, c = f & 15;
            *(uint4*)(&al[r * 136 + c * 8]) = v;
        }
    }
    __syncthreads();

    f32x4 acc[8];
#pragma unroll
    for (int nt = 0; nt < 8; nt++) acc[nt] = (f32x4){0.f, 0.f, 0.f, 0.f};

    const int arow = wave * 16 + lane15;
#pragma unroll
    for (int kt = 0; kt < 4; kt++) {
        bf16x8 af = *(const bf16x8*)(&al[arow * 136 + kt * 32 + quad * 8]);
#pragma unroll
        for (int nt = 0; nt < 8; nt++) {
            bf16x8 bfr = *(const bf16x8*)(&wl[(nt * 16 + lane15) * 136 + kt * 32 + quad * 8]);
            acc[nt] = __builtin_amdgcn_mfma_f32_16x16x32_bf16(af, bfr, acc[nt], 0, 0, 0);
        }
    }

    const int rbase = m0 + wave * 16 + quad * 4;
    float dsc[4];
#pragma unroll
    for (int r = 0; r < 4; r++)
        dsc[r] = (rbase + r < n) ? dinv[rbase + r] : 0.f;
#pragma unroll
    for (int nt = 0; nt < 8; nt++) {
        int c0 = nt * 16 + lane15;
#pragma unroll
        for (int r = 0; r < 4; r += 2) {
            int pk = __builtin_amdgcn_cvt_pk_fp8_f32(acc[nt][r] * dsc[r],
                                                     acc[nt][r + 1] * dsc[r + 1], 0, false);
            int row0 = rbase + r, row1 = rbase + r + 1;
            if (row0 < n) C[(size_t)row0 * 128 + c0] = (uint8_t)pk;
            if (row1 < n) C[(size_t)row1 * 128 + c0] = (uint8_t)(pk >> 8);
        }
    }
}

// ---------------- Aggregation: clamped-masked 16-batches, 2-deep A/B pipeline ----------------
// Change vs R2: no 8/1 tail loops (serial round-trips). All batches are 16-wide with
// OOB slots clamped to the last edge (dup gather = L1 hit) and zeroed at consume time
// (fp8 0x00 decodes to 0.0). Batch k+1's gathers issue BEFORE batch k is consumed.
#define AGG_ISSUE(buf, eb)                                                            \
    {                                                                                 \
        _Pragma("unroll")                                                             \
        for (int i = 0; i < 16; i++) {                                                \
            int idx = (eb) + i;                                                       \
            idx = (idx < e1) ? idx : last;                                            \
            int u = __builtin_amdgcn_readfirstlane(csr[idx]);                         \
            buf[i] = (uint32_t)xw[(size_t)u * 64 + l];                                \
        }                                                                             \
    }
#define AGG_CONSUME_FULL(buf)                                                         \
    {                                                                                 \
        _Pragma("unroll")                                                             \
        for (int i = 0; i < 16; i++) {                                                \
            f32x2 f = __builtin_amdgcn_cvt_pk_f32_fp8((int)buf[i], false);            \
            ax += f.x; ay += f.y;                                                     \
        }                                                                             \
    }
#define AGG_CONSUME_MASK(buf, eb)                                                     \
    {                                                                                 \
        _Pragma("unroll")                                                             \
        for (int i = 0; i < 16; i++) {                                                \
            uint32_t q = ((eb) + i < e1) ? buf[i] : 0u;                               \
            f32x2 f = __builtin_amdgcn_cvt_pk_f32_fp8((int)q, false);                 \
            ax += f.x; ay += f.y;                                                     \
        }                                                                             \
    }

__global__ __launch_bounds__(256) void k_agg(const ushort_t* __restrict__ xw,   // fp8 pairs
                                             const int* __restrict__ offsets,
                                             const int* __restrict__ csr,
                                             const float* __restrict__ dinv,
                                             const float* __restrict__ bias,
                                             ushort_t* __restrict__ out, int n) {
    const int l = threadIdx.x & 63;
    const int wave = (blockIdx.x << 2) | (threadIdx.x >> 6);
    const int wstride = gridDim.x << 2;
    const float2 bb = ((const float2*)bias)[l];
    uint32_t* out32 = (uint32_t*)out;

    for (int v = wave; v < n; v += wstride) {
        uint32_t pv = (uint32_t)xw[(size_t)v * 64 + l];
        f32x2 fs = __builtin_amdgcn_cvt_pk_f32_fp8((int)pv, false);
        float ax = fs.x, ay = fs.y;

        int e  = __builtin_amdgcn_readfirstlane(offsets[v]);
        int e1 = __builtin_amdgcn_readfirstlane(offsets[v + 1]);

        if (e < e1) {
            const int last = e1 - 1;
            uint32_t pA[16], pB[16];
            int eb = e;
            AGG_ISSUE(pA, eb);
            bool curA = true;
            for (;;) {
                int ebn = eb + 16;
                if (ebn >= e1) break;          // current batch is the last one
                if (curA) {
                    AGG_ISSUE(pB, ebn);
                    AGG_CONSUME_FULL(pA);      // fully valid (ebn < e1 => 16 valid)
                } else {
                    AGG_ISSUE(pA, ebn);
                    AGG_CONSUME_FULL(pB);
                }
                curA = !curA;
                eb = ebn;
            }
            if (curA) { AGG_CONSUME_MASK(pA, eb); }
            else      { AGG_CONSUME_MASK(pB, eb); }
        }

        float dv = dinv[v];
        float ox = fmaxf(fmaf(ax, dv, bb.x), 0.f);
        float oy = fmaxf(fmaf(ay, dv, bb.y), 0.f);
        out32[(size_t)v * 64 + l] = ((uint32_t)f2bf(oy) << 16) | (uint32_t)f2bf(ox);
    }
}

// ---------------- Fused mean-pool + FC (separate 256-block kernel; proven) ----------------
__global__ __launch_bounds__(256) void k_poolfc(const ushort_t* __restrict__ h,
                                                float* __restrict__ pooled, int n,
                                                const float* __restrict__ Wfc,
                                                const float* __restrict__ bfc,
                                                float* __restrict__ out, float invN,
                                                int* __restrict__ counter) {
    __shared__ float red[512];
    __shared__ int lastFlag;
    __shared__ float pl[128];
    const int t = threadIdx.x;
    const int l = t & 63;
    const int wv = (blockIdx.x << 2) | (t >> 6);
    const int ws = gridDim.x << 2;
    const uint32_t* h32 = (const uint32_t*)h;

    const int span = (n + ws - 1) / ws;
    int r0 = wv * span;
    int r1 = min(n, r0 + span);
    float sx = 0.f, sy = 0.f;
    int r = r0;
    for (; r + 3 < r1; r += 4) {
        uint32_t p0 = h32[(size_t)r * 64 + l];
        uint32_t p1 = h32[(size_t)(r + 1) * 64 + l];
        uint32_t p2 = h32[(size_t)(r + 2) * 64 + l];
        uint32_t p3 = h32[(size_t)(r + 3) * 64 + l];
        sx += bf_lo(p0) + bf_lo(p1) + bf_lo(p2) + bf_lo(p3);
        sy += bf_hi(p0) + bf_hi(p1) + bf_hi(p2) + bf_hi(p3);
    }
    for (; r < r1; r++) {
        uint32_t p = h32[(size_t)r * 64 + l];
        sx += bf_lo(p); sy += bf_hi(p);
    }
    red[t] = sx;
    red[256 + t] = sy;
    __syncthreads();
    float* slice = pooled + (blockIdx.x & (PSLICES - 1)) * 128;
    if (t < 64) {
        sx = red[t] + red[t + 64] + red[t + 128] + red[t + 192];
        sy = red[256 + t] + red[256 + t + 64] + red[256 + t + 128] + red[256 + t + 192];
        atomicAdd(&slice[2 * l], sx);
        atomicAdd(&slice[2 * l + 1], sy);
    }
    __threadfence();
    __syncthreads();
    if (t == 0) {
        int old = atomicAdd(counter, 1);
        lastFlag = (old == (int)gridDim.x - 1);
    }
    __syncthreads();
    if (lastFlag) {
        if (t < 128) {
            float acc = 0.f;
#pragma unroll
            for (int s = 0; s < PSLICES; s++)
                acc += atomicAdd(&pooled[s * 128 + t], 0.f);   // coherent read
            pl[t] = acc;
        }
        __syncthreads();
        if (t < 128) {
            float acc = bfc[t];
#pragma unroll 8
            for (int k = 0; k < 128; k++)
                acc = fmaf(pl[k] * invN, Wfc[k * 128 + t], acc);
            out[t] = acc;
        }
    }
}

// ---------------- launcher ----------------
extern "C" void kernel_launch(void* const* d_in, const int* in_sizes, int n_in,
                              void* d_out, int out_size, void* d_ws, size_t ws_size,
                              hipStream_t stream) {
    const float* x    = (const float*)d_in[0];
    const int*   ei   = (const int*)d_in[1];
    const float* W1   = (const float*)d_in[2];
    const float* b1   = (const float*)d_in[3];
    const float* W2   = (const float*)d_in[4];
    const float* b2   = (const float*)d_in[5];
    const float* Wfc  = (const float*)d_in[6];
    const float* bfc  = (const float*)d_in[7];
    float*       out  = (float*)d_out;

    const int n = in_sizes[0] / 128;
    const int E = in_sizes[1] / 2;
    const int* src = ei;
    const int* dst = ei + E;
    const int NB = (n + BKT_W - 1) >> BKT_SHIFT;   // 782

    char* w = (char*)d_ws;
    uint8_t*  xwq = (uint8_t*)w;  w += (size_t)n * 128;                 // fp8 [n][128]
    ushort_t* h   = (ushort_t*)w; w += (size_t)n * 128 * sizeof(ushort_t);
    int*      csr = (int*)w;      w += (size_t)E * sizeof(int);
    uint32_t* bpack = (uint32_t*)w; w += (size_t)NB * BCAP * sizeof(uint32_t);
    float* dinv = (float*)w;  w += (size_t)n * sizeof(float);
    int*   offs = (int*)w;    w += (size_t)(n + 1) * sizeof(int);
    w = (char*)(((uintptr_t)w + 127) & ~(uintptr_t)127);
    int*   bcnt  = (int*)w;   w += NB_MAX * sizeof(int);
    int*   counter = (int*)w; w += 32 * sizeof(int);
    float* pooled = (float*)w; w += PSLICES * 128 * sizeof(float);
    ushort_t* Wt1 = (ushort_t*)w; w += 16384 * sizeof(ushort_t);
    ushort_t* Wt2 = (ushort_t*)w; w += 16384 * sizeof(ushort_t);

    const int ntiles64 = (n + 63) / 64;
    const float invN = 1.0f / (float)n;

    kW_init<<<65, 256, 0, stream>>>(W1, W2, Wt1, Wt2, bcnt, pooled, counter);
    kB_bucket<<<(E + KB_CHUNK - 1) / KB_CHUNK, 256, 0, stream>>>(src, dst, E, NB, bcnt, bpack);
    kC_csr<<<NB, 256, 0, stream>>>(bpack, bcnt, NB, n, dinv, offs, csr);
    k_gemm1<<<ntiles64, 256, 0, stream>>>(x, Wt1, dinv, xwq, n);

    k_agg<<<8192, 256, 0, stream>>>((const ushort_t*)xwq, offs, csr, dinv, b1, h, n);
    k_gemm_mfma<<<ntiles64, 256, 0, stream>>>(h, Wt2, dinv, xwq, n);
    k_agg<<<8192, 256, 0, stream>>>((const ushort_t*)xwq, offs, csr, dinv, b2, h, n);

    k_poolfc<<<256, 256, 0, stream>>>(h, pooled, n, Wfc, bfc, out, invN, counter);
}

// Round 4
// 271.960 us; speedup vs baseline: 1.2098x; 1.2098x over previous
//
#include <hip/hip_runtime.h>
#include <stdint.h>

typedef unsigned short ushort_t;
typedef __attribute__((ext_vector_type(8))) short bf16x8;   // 8 bf16 in 4 VGPRs
typedef __attribute__((ext_vector_type(4))) float f32x4;
typedef __attribute__((ext_vector_type(2))) float f32x2;

#define BKT_SHIFT 7
#define BKT_W     128
#define NB_MAX    1024
#define KB_ITERS  16
#define KB_CHUNK  (256 * KB_ITERS)   // 4096 edges per block
#define BCAP      2560               // lambda=2048, +11 sigma
#define CSTRIDE   2944               // BCAP + 128*3 pad headroom; multiple of 128
#define PSLICES   8

// ---------------- helpers ----------------

__device__ __forceinline__ ushort_t f2bf(float f) {
    union { float f; uint32_t u; } a; a.f = f;
    uint32_t u = a.u;
    uint32_t r = (u + 0x7FFFu + ((u >> 16) & 1u)) >> 16;
    return (ushort_t)r;
}
__device__ __forceinline__ float bf_lo(uint32_t p) { return __uint_as_float(p << 16); }
__device__ __forceinline__ float bf_hi(uint32_t p) { return __uint_as_float(p & 0xFFFF0000u); }

// ---------------- kW_init: weight convert + zero small state + zero sentinel row ----------------
__global__ __launch_bounds__(256) void kW_init(const float* __restrict__ W1,
                                               const float* __restrict__ W2,
                                               ushort_t* __restrict__ Wt1,
                                               ushort_t* __restrict__ Wt2,
                                               int* __restrict__ bcnt,
                                               float* __restrict__ pooled,   // PSLICES*128
                                               int* __restrict__ counter,
                                               uint8_t* __restrict__ xwq, int n) {
    int b = blockIdx.x, t = threadIdx.x;
    if (b < 64) {
        int i = b * 256 + t;
        int k = i >> 7, nn = i & 127;
        Wt1[nn * 128 + k] = f2bf(W1[i]);
        Wt2[nn * 128 + k] = f2bf(W2[i]);
    } else {
        for (int i = t; i < NB_MAX; i += 256) bcnt[i] = 0;
        for (int i = t; i < PSLICES * 128; i += 256) pooled[i] = 0.f;
        if (t < 32) ((uint32_t*)(xwq + (size_t)n * 128))[t] = 0u;   // sentinel zero-row
        if (t == 0) *counter = 0;
    }
}

// ---------------- kB_bucket: single-pass scatter into fixed-stride buckets ----------------
// bucket b occupies bpack[b*BCAP .. b*BCAP + bcnt[b]).  pack = (src<<7)|(dst&127)
__global__ __launch_bounds__(256) void kB_bucket(const int* __restrict__ src,
                                                 const int* __restrict__ dst, int E, int NB,
                                                 int* __restrict__ bcnt,
                                                 uint32_t* __restrict__ bpack) {
    __shared__ int lh[NB_MAX];
    int t = threadIdx.x;
    for (int i = t; i < NB; i += 256) lh[i] = 0;
    __syncthreads();

    int base = blockIdx.x * KB_CHUNK;
    int dreg[KB_ITERS], rank[KB_ITERS];
#pragma unroll
    for (int i = 0; i < KB_ITERS; i++) {
        int e = base + t + i * 256;
        if (e < E) {
            int d = dst[e];
            dreg[i] = d;
            rank[i] = atomicAdd(&lh[d >> BKT_SHIFT], 1);
        } else {
            dreg[i] = -1; rank[i] = 0;
        }
    }
    __syncthreads();
    // reserve a contiguous range per touched bucket (global cursor, no prescan)
    for (int i = t; i < NB; i += 256) {
        int c = lh[i];
        lh[i] = c ? atomicAdd(&bcnt[i], c) : 0;
    }
    __syncthreads();
#pragma unroll
    for (int i = 0; i < KB_ITERS; i++) {
        int e = base + t + i * 256;
        if (dreg[i] >= 0) {
            int d = dreg[i];
            int bkt = d >> BKT_SHIFT;
            size_t pos = (size_t)bkt * BCAP + lh[bkt] + rank[i];
            bpack[pos] = ((uint32_t)src[e] << BKT_SHIFT) | (uint32_t)(d & (BKT_W - 1));
        }
    }
}

// ---------------- kC_csr: per-bucket CSR build, 4-padded segments, fixed-stride output ----------
// Node v's edges live in csr[offs[v] .. ends[v]) with ends-offs a multiple of 4; pad slots
// hold index n (zero row).  No global bucket scan needed (fixed stride).
__global__ __launch_bounds__(256) void kC_csr(const uint32_t* __restrict__ bpack,
                                              const int* __restrict__ bcnt, int NB, int n,
                                              float* __restrict__ dinv,
                                              int* __restrict__ offs,
                                              int* __restrict__ ends,
                                              int* __restrict__ csr) {
    __shared__ int pr[BKT_W];
    __shared__ int cnt[BKT_W];
    __shared__ int cur[BKT_W];
    __shared__ int pend[BKT_W];

    const int t = threadIdx.x;
    const int b = blockIdx.x;
    const int nb0 = b << BKT_SHIFT;
    const int wlen = min(BKT_W, n - nb0);
    const int cntb = bcnt[b];
    const uint32_t* bp = bpack + (size_t)b * BCAP;
    const int base = b * CSTRIDE;

    if (t < BKT_W) cnt[t] = 0;
    __syncthreads();
    for (int e = t; e < cntb; e += 256)
        atomicAdd(&cnt[bp[e] & (BKT_W - 1)], 1);
    __syncthreads();

    int v = (t < BKT_W) ? cnt[t] : 0;
    int pv = (v + 3) & ~3;                 // padded per-node length
    if (t < BKT_W) pr[t] = pv;
    __syncthreads();
    for (int off = 1; off < BKT_W; off <<= 1) {
        int x = (t >= off && t < BKT_W) ? pr[t - off] : 0;
        __syncthreads();
        if (t < BKT_W) pr[t] += x;
        __syncthreads();
    }
    if (t < BKT_W) {
        int st = base + pr[t] - pv;
        cur[t] = st;
        pend[t] = st + pv;
        if (t < wlen) {
            offs[nb0 + t] = st;
            ends[nb0 + t] = st + pv;
            dinv[nb0 + t] = rsqrtf((float)(v + 1));   // true count, not padded
        }
    }
    __syncthreads();

    for (int e = t; e < cntb; e += 256) {
        uint32_t p = bp[e];
        int pos = atomicAdd(&cur[p & (BKT_W - 1)], 1);
        csr[pos] = (int)(p >> BKT_SHIFT);
    }
    __syncthreads();
    // fill pad slots with sentinel (zero row); cur[t] == st+v after scatter
    if (t < BKT_W) {
        int qe = pend[t];
        for (int q = cur[t]; q < qe; q++) csr[q] = n;
    }
}

// ---------------- k_gemm1: layer-1 GEMM, f32 in (x), fp8 out (xw1), dinv-scaled ----------------
__global__ __launch_bounds__(256) void k_gemm1(const float* __restrict__ x,
                                               const ushort_t* __restrict__ Wt,
                                               const float* __restrict__ dinv,
                                               uint8_t* __restrict__ C, int n) {
    __shared__ ushort_t al[64 * 136];
    __shared__ ushort_t wl[128 * 136];
    const int t = threadIdx.x;
    const int l = t & 63;
    const int wave = t >> 6;
    const int lane15 = l & 15;
    const int quad = l >> 4;
    const int m0 = blockIdx.x * 64;
    const int rows = min(64, n - m0);

#pragma unroll
    for (int i = 0; i < 8; i++) {
        int f = t + 256 * i;
        int r = f >> 4, c = f & 15;
        *(uint4*)(&wl[r * 136 + c * 8]) = ((const uint4*)Wt)[f];
    }
    {
        const float4* Ap = (const float4*)(x + (size_t)m0 * 128);
        int nf = rows * 32;
#pragma unroll
        for (int i = 0; i < 8; i++) {
            int f = t + 256 * i;
            float4 vv = make_float4(0.f, 0.f, 0.f, 0.f);
            if (f < nf) vv = Ap[f];
            ushort4 us;
            us.x = f2bf(vv.x); us.y = f2bf(vv.y); us.z = f2bf(vv.z); us.w = f2bf(vv.w);
            int r = f >> 5, c = f & 31;
            *(ushort4*)(&al[r * 136 + c * 4]) = us;
        }
    }
    __syncthreads();

    f32x4 acc[8];
#pragma unroll
    for (int nt = 0; nt < 8; nt++) acc[nt] = (f32x4){0.f, 0.f, 0.f, 0.f};

    const int arow = wave * 16 + lane15;
#pragma unroll
    for (int kt = 0; kt < 4; kt++) {
        bf16x8 af = *(const bf16x8*)(&al[arow * 136 + kt * 32 + quad * 8]);
#pragma unroll
        for (int nt = 0; nt < 8; nt++) {
            bf16x8 bfr = *(const bf16x8*)(&wl[(nt * 16 + lane15) * 136 + kt * 32 + quad * 8]);
            acc[nt] = __builtin_amdgcn_mfma_f32_16x16x32_bf16(af, bfr, acc[nt], 0, 0, 0);
        }
    }

    const int rbase = m0 + wave * 16 + quad * 4;
    float dsc[4];
#pragma unroll
    for (int r = 0; r < 4; r++)
        dsc[r] = (rbase + r < n) ? dinv[rbase + r] : 0.f;
#pragma unroll
    for (int nt = 0; nt < 8; nt++) {
        int c0 = nt * 16 + lane15;
#pragma unroll
        for (int r = 0; r < 4; r += 2) {
            int pk = __builtin_amdgcn_cvt_pk_fp8_f32(acc[nt][r] * dsc[r],
                                                     acc[nt][r + 1] * dsc[r + 1], 0, false);
            int row0 = rbase + r, row1 = rbase + r + 1;
            if (row0 < n) C[(size_t)row0 * 128 + c0] = (uint8_t)pk;
            if (row1 < n) C[(size_t)row1 * 128 + c0] = (uint8_t)(pk >> 8);
        }
    }
}

// ---------------- MFMA GEMM (layer 2): bf16 in (h), fp8 out (xw2), dinv-scaled ----------------
__global__ __launch_bounds__(256) void k_gemm_mfma(const ushort_t* __restrict__ A,
                                                   const ushort_t* __restrict__ Wt,
                                                   const float* __restrict__ dinv,
                                                   uint8_t* __restrict__ C, int n) {
    __shared__ ushort_t al[64 * 136];
    __shared__ ushort_t wl[128 * 136];
    const int t = threadIdx.x;
    const int l = t & 63;
    const int wave = t >> 6;
    const int lane15 = l & 15;
    const int quad = l >> 4;
    const int m0 = blockIdx.x * 64;
    const int rows = min(64, n - m0);

#pragma unroll
    for (int i = 0; i < 8; i++) {
        int f = t + 256 * i;
        int r = f >> 4, c = f & 15;
        *(uint4*)(&wl[r * 136 + c * 8]) = ((const uint4*)Wt)[f];
    }
    {
        const uint4* Ap = (const uint4*)(A + (size_t)m0 * 128);
        int nf = rows * 16;
#pragma unroll
        for (int i = 0; i < 4; i++) {
            int f = t + 256 * i;
            uint4 v = make_uint4(0, 0, 0, 0);
            if (f < nf) v = Ap[f];
            int r = f >> 4, c = f & 15;
            *(uint4*)(&al[r * 136 + c * 8]) = v;
        }
    }
    __syncthreads();

    f32x4 acc[8];
#pragma unroll
    for (int nt = 0; nt < 8; nt++) acc[nt] = (f32x4){0.f, 0.f, 0.f, 0.f};

    const int arow = wave * 16 + lane15;
#pragma unroll
    for (int kt = 0; kt < 4; kt++) {
        bf16x8 af = *(const bf16x8*)(&al[arow * 136 + kt * 32 + quad * 8]);
#pragma unroll
        for (int nt = 0; nt < 8; nt++) {
            bf16x8 bfr = *(const bf16x8*)(&wl[(nt * 16 + lane15) * 136 + kt * 32 + quad * 8]);
            acc[nt] = __builtin_amdgcn_mfma_f32_16x16x32_bf16(af, bfr, acc[nt], 0, 0, 0);
        }
    }

    const int rbase = m0 + wave * 16 + quad * 4;
    float dsc[4];
#pragma unroll
    for (int r = 0; r < 4; r++)
        dsc[r] = (rbase + r < n) ? dinv[rbase + r] : 0.f;
#pragma unroll
    for (int nt = 0; nt < 8; nt++) {
        int c0 = nt * 16 + lane15;
#pragma unroll
        for (int r = 0; r < 4; r += 2) {
            int pk = __builtin_amdgcn_cvt_pk_fp8_f32(acc[nt][r] * dsc[r],
                                                     acc[nt][r + 1] * dsc[r + 1], 0, false);
            int row0 = rbase + r, row1 = rbase + r + 1;
            if (row0 < n) C[(size_t)row0 * 128 + c0] = (uint8_t)pk;
            if (row1 < n) C[(size_t)row1 * 128 + c0] = (uint8_t)(pk >> 8);
        }
    }
}

// ---------------- Aggregation: proven 16/8 geometry, int4 csr loads, exact 4-padded segments --
// Segments are multiples of 4 and 4-aligned (pad slots -> zero row n). No singles tail,
// no masking, no duplicate gathers. csr index loads are dwordx4 (4x fewer requests).
__global__ __launch_bounds__(256) void k_agg(const ushort_t* __restrict__ xw,   // fp8 pairs
                                             const int* __restrict__ offsets,
                                             const int* __restrict__ ends,
                                             const int* __restrict__ csr,
                                             const float* __restrict__ dinv,
                                             const float* __restrict__ bias,
                                             ushort_t* __restrict__ out, int n) {
    const int l = threadIdx.x & 63;
    const int wave = (blockIdx.x << 2) | (threadIdx.x >> 6);
    const int wstride = gridDim.x << 2;
    const float2 bb = ((const float2*)bias)[l];
    uint32_t* out32 = (uint32_t*)out;

    for (int v = wave; v < n; v += wstride) {
        uint32_t pv = (uint32_t)xw[(size_t)v * 64 + l];
        f32x2 fs = __builtin_amdgcn_cvt_pk_f32_fp8((int)pv, false);
        float ax = fs.x, ay = fs.y;

        int e  = __builtin_amdgcn_readfirstlane(offsets[v]);
        int e1 = __builtin_amdgcn_readfirstlane(ends[v]);

        for (; e + 15 < e1; e += 16) {
            const int4* c4 = (const int4*)(csr + e);
            int4 w0 = c4[0], w1 = c4[1], w2 = c4[2], w3 = c4[3];
            int u[16];
            u[0]  = __builtin_amdgcn_readfirstlane(w0.x);
            u[1]  = __builtin_amdgcn_readfirstlane(w0.y);
            u[2]  = __builtin_amdgcn_readfirstlane(w0.z);
            u[3]  = __builtin_amdgcn_readfirstlane(w0.w);
            u[4]  = __builtin_amdgcn_readfirstlane(w1.x);
            u[5]  = __builtin_amdgcn_readfirstlane(w1.y);
            u[6]  = __builtin_amdgcn_readfirstlane(w1.z);
            u[7]  = __builtin_amdgcn_readfirstlane(w1.w);
            u[8]  = __builtin_amdgcn_readfirstlane(w2.x);
            u[9]  = __builtin_amdgcn_readfirstlane(w2.y);
            u[10] = __builtin_amdgcn_readfirstlane(w2.z);
            u[11] = __builtin_amdgcn_readfirstlane(w2.w);
            u[12] = __builtin_amdgcn_readfirstlane(w3.x);
            u[13] = __builtin_amdgcn_readfirstlane(w3.y);
            u[14] = __builtin_amdgcn_readfirstlane(w3.z);
            u[15] = __builtin_amdgcn_readfirstlane(w3.w);
            uint32_t p[16];
#pragma unroll
            for (int i = 0; i < 16; i++) p[i] = (uint32_t)xw[(size_t)u[i] * 64 + l];
#pragma unroll
            for (int i = 0; i < 16; i++) {
                f32x2 f = __builtin_amdgcn_cvt_pk_f32_fp8((int)p[i], false);
                ax += f.x; ay += f.y;
            }
        }
        for (; e + 7 < e1; e += 8) {
            const int4* c4 = (const int4*)(csr + e);
            int4 w0 = c4[0], w1 = c4[1];
            int u[8];
            u[0] = __builtin_amdgcn_readfirstlane(w0.x);
            u[1] = __builtin_amdgcn_readfirstlane(w0.y);
            u[2] = __builtin_amdgcn_readfirstlane(w0.z);
            u[3] = __builtin_amdgcn_readfirstlane(w0.w);
            u[4] = __builtin_amdgcn_readfirstlane(w1.x);
            u[5] = __builtin_amdgcn_readfirstlane(w1.y);
            u[6] = __builtin_amdgcn_readfirstlane(w1.z);
            u[7] = __builtin_amdgcn_readfirstlane(w1.w);
            uint32_t p[8];
#pragma unroll
            for (int i = 0; i < 8; i++) p[i] = (uint32_t)xw[(size_t)u[i] * 64 + l];
#pragma unroll
            for (int i = 0; i < 8; i++) {
                f32x2 f = __builtin_amdgcn_cvt_pk_f32_fp8((int)p[i], false);
                ax += f.x; ay += f.y;
            }
        }
        for (; e + 3 < e1; e += 4) {
            int4 w0 = *(const int4*)(csr + e);
            int u[4];
            u[0] = __builtin_amdgcn_readfirstlane(w0.x);
            u[1] = __builtin_amdgcn_readfirstlane(w0.y);
            u[2] = __builtin_amdgcn_readfirstlane(w0.z);
            u[3] = __builtin_amdgcn_readfirstlane(w0.w);
            uint32_t p[4];
#pragma unroll
            for (int i = 0; i < 4; i++) p[i] = (uint32_t)xw[(size_t)u[i] * 64 + l];
#pragma unroll
            for (int i = 0; i < 4; i++) {
                f32x2 f = __builtin_amdgcn_cvt_pk_f32_fp8((int)p[i], false);
                ax += f.x; ay += f.y;
            }
        }

        float dv = dinv[v];
        float ox = fmaxf(fmaf(ax, dv, bb.x), 0.f);
        float oy = fmaxf(fmaf(ay, dv, bb.y), 0.f);
        out32[(size_t)v * 64 + l] = ((uint32_t)f2bf(oy) << 16) | (uint32_t)f2bf(ox);
    }
}

// ---------------- Fused mean-pool + FC (separate 256-block kernel; proven) ----------------
__global__ __launch_bounds__(256) void k_poolfc(const ushort_t* __restrict__ h,
                                                float* __restrict__ pooled, int n,
                                                const float* __restrict__ Wfc,
                                                const float* __restrict__ bfc,
                                                float* __restrict__ out, float invN,
                                                int* __restrict__ counter) {
    __shared__ float red[512];
    __shared__ int lastFlag;
    __shared__ float pl[128];
    const int t = threadIdx.x;
    const int l = t & 63;
    const int wv = (blockIdx.x << 2) | (t >> 6);
    const int ws = gridDim.x << 2;
    const uint32_t* h32 = (const uint32_t*)h;

    const int span = (n + ws - 1) / ws;
    int r0 = wv * span;
    int r1 = min(n, r0 + span);
    float sx = 0.f, sy = 0.f;
    int r = r0;
    for (; r + 3 < r1; r += 4) {
        uint32_t p0 = h32[(size_t)r * 64 + l];
        uint32_t p1 = h32[(size_t)(r + 1) * 64 + l];
        uint32_t p2 = h32[(size_t)(r + 2) * 64 + l];
        uint32_t p3 = h32[(size_t)(r + 3) * 64 + l];
        sx += bf_lo(p0) + bf_lo(p1) + bf_lo(p2) + bf_lo(p3);
        sy += bf_hi(p0) + bf_hi(p1) + bf_hi(p2) + bf_hi(p3);
    }
    for (; r < r1; r++) {
        uint32_t p = h32[(size_t)r * 64 + l];
        sx += bf_lo(p); sy += bf_hi(p);
    }
    red[t] = sx;
    red[256 + t] = sy;
    __syncthreads();
    float* slice = pooled + (blockIdx.x & (PSLICES - 1)) * 128;
    if (t < 64) {
        sx = red[t] + red[t + 64] + red[t + 128] + red[t + 192];
        sy = red[256 + t] + red[256 + t + 64] + red[256 + t + 128] + red[256 + t + 192];
        atomicAdd(&slice[2 * l], sx);
        atomicAdd(&slice[2 * l + 1], sy);
    }
    __threadfence();
    __syncthreads();
    if (t == 0) {
        int old = atomicAdd(counter, 1);
        lastFlag = (old == (int)gridDim.x - 1);
    }
    __syncthreads();
    if (lastFlag) {
        if (t < 128) {
            float acc = 0.f;
#pragma unroll
            for (int s = 0; s < PSLICES; s++)
                acc += atomicAdd(&pooled[s * 128 + t], 0.f);   // coherent read
            pl[t] = acc;
        }
        __syncthreads();
        if (t < 128) {
            float acc = bfc[t];
#pragma unroll 8
            for (int k = 0; k < 128; k++)
                acc = fmaf(pl[k] * invN, Wfc[k * 128 + t], acc);
            out[t] = acc;
        }
    }
}

// ---------------- launcher ----------------
extern "C" void kernel_launch(void* const* d_in, const int* in_sizes, int n_in,
                              void* d_out, int out_size, void* d_ws, size_t ws_size,
                              hipStream_t stream) {
    const float* x    = (const float*)d_in[0];
    const int*   ei   = (const int*)d_in[1];
    const float* W1   = (const float*)d_in[2];
    const float* b1   = (const float*)d_in[3];
    const float* W2   = (const float*)d_in[4];
    const float* b2   = (const float*)d_in[5];
    const float* Wfc  = (const float*)d_in[6];
    const float* bfc  = (const float*)d_in[7];
    float*       out  = (float*)d_out;

    const int n = in_sizes[0] / 128;
    const int E = in_sizes[1] / 2;
    const int* src = ei;
    const int* dst = ei + E;
    const int NB = (n + BKT_W - 1) >> BKT_SHIFT;   // 782

    char* w = (char*)d_ws;
    uint8_t*  xwq = (uint8_t*)w;  w += (size_t)(n + 1) * 128;           // fp8 [n+1][128], row n = zeros
    ushort_t* h   = (ushort_t*)w; w += (size_t)n * 128 * sizeof(ushort_t);
    int*      csr = (int*)w;      w += (size_t)NB * CSTRIDE * sizeof(int);
    uint32_t* bpack = (uint32_t*)w; w += (size_t)NB * BCAP * sizeof(uint32_t);
    float* dinv = (float*)w;  w += (size_t)n * sizeof(float);
    int*   offs = (int*)w;    w += (size_t)n * sizeof(int);
    int*   ends = (int*)w;    w += (size_t)n * sizeof(int);
    w = (char*)(((uintptr_t)w + 127) & ~(uintptr_t)127);
    int*   bcnt  = (int*)w;   w += NB_MAX * sizeof(int);
    int*   counter = (int*)w; w += 32 * sizeof(int);
    float* pooled = (float*)w; w += PSLICES * 128 * sizeof(float);
    ushort_t* Wt1 = (ushort_t*)w; w += 16384 * sizeof(ushort_t);
    ushort_t* Wt2 = (ushort_t*)w; w += 16384 * sizeof(ushort_t);

    const int ntiles64 = (n + 63) / 64;
    const float invN = 1.0f / (float)n;

    kW_init<<<65, 256, 0, stream>>>(W1, W2, Wt1, Wt2, bcnt, pooled, counter, xwq, n);
    kB_bucket<<<(E + KB_CHUNK - 1) / KB_CHUNK, 256, 0, stream>>>(src, dst, E, NB, bcnt, bpack);
    kC_csr<<<NB, 256, 0, stream>>>(bpack, bcnt, NB, n, dinv, offs, ends, csr);
    k_gemm1<<<ntiles64, 256, 0, stream>>>(x, Wt1, dinv, xwq, n);

    k_agg<<<8192, 256, 0, stream>>>((const ushort_t*)xwq, offs, ends, csr, dinv, b1, h, n);
    k_gemm_mfma<<<ntiles64, 256, 0, stream>>>(h, Wt2, dinv, xwq, n);
    k_agg<<<8192, 256, 0, stream>>>((const ushort_t*)xwq, offs, ends, csr, dinv, b2, h, n);

    k_poolfc<<<256, 256, 0, stream>>>(h, pooled, n, Wfc, bfc, out, invN, counter);
}

// Round 5
// 268.906 us; speedup vs baseline: 1.2235x; 1.0114x over previous
//
#include <hip/hip_runtime.h>
#include <stdint.h>

typedef unsigned short ushort_t;
typedef __attribute__((ext_vector_type(8))) short bf16x8;   // 8 bf16 in 4 VGPRs
typedef __attribute__((ext_vector_type(4))) float f32x4;
typedef __attribute__((ext_vector_type(2))) float f32x2;

#define BKT_SHIFT 7
#define BKT_W     128
#define NB_MAX    1024
#define KB_THREADS 1024
#define KB_EPT    4
#define KB_CHUNK  (KB_THREADS * KB_EPT)   // 4096 edges per block, 16 waves
#define BCAP      2560               // lambda=2048, +11 sigma
#define CSTRIDE   2944               // BCAP + 128*3 pad headroom; multiple of 128
#define PSLICES   8

// ---------------- helpers ----------------

__device__ __forceinline__ ushort_t f2bf(float f) {
    union { float f; uint32_t u; } a; a.f = f;
    uint32_t u = a.u;
    uint32_t r = (u + 0x7FFFu + ((u >> 16) & 1u)) >> 16;
    return (ushort_t)r;
}
__device__ __forceinline__ float bf_lo(uint32_t p) { return __uint_as_float(p << 16); }
__device__ __forceinline__ float bf_hi(uint32_t p) { return __uint_as_float(p & 0xFFFF0000u); }

// ---------------- kW_init: weight convert + zero small state + zero sentinel row ----------------
__global__ __launch_bounds__(256) void kW_init(const float* __restrict__ W1,
                                               const float* __restrict__ W2,
                                               ushort_t* __restrict__ Wt1,
                                               ushort_t* __restrict__ Wt2,
                                               int* __restrict__ bcnt,
                                               float* __restrict__ pooled,   // PSLICES*128
                                               int* __restrict__ counter,
                                               uint8_t* __restrict__ xwq, int n) {
    int b = blockIdx.x, t = threadIdx.x;
    if (b < 64) {
        int i = b * 256 + t;
        int k = i >> 7, nn = i & 127;
        Wt1[nn * 128 + k] = f2bf(W1[i]);
        Wt2[nn * 128 + k] = f2bf(W2[i]);
    } else {
        for (int i = t; i < NB_MAX; i += 256) bcnt[i] = 0;
        for (int i = t; i < PSLICES * 128; i += 256) pooled[i] = 0.f;
        if (t < 32) ((uint32_t*)(xwq + (size_t)n * 128))[t] = 0u;   // sentinel zero-row
        if (t == 0) *counter = 0;
    }
}

// ---------------- kB_bucket: 1024-thread blocks, int4 edge loads, LDS histogram ----------------
// bucket b occupies bpack[b*BCAP .. b*BCAP + bcnt[b]).  pack = (src<<7)|(dst&127)
// R5: 16 waves/block (occupancy fix; was 4 waves -> 11.6% occupancy), 4 edges/thread
// via dwordx4. Chunk stays 4096 edges so the histogram keeps its ~5:1 atomic compression.
__global__ __launch_bounds__(KB_THREADS) void kB_bucket(const int* __restrict__ src,
                                                        const int* __restrict__ dst, int E, int NB,
                                                        int* __restrict__ bcnt,
                                                        uint32_t* __restrict__ bpack) {
    __shared__ int lh[NB_MAX];
    const int t = threadIdx.x;
    for (int i = t; i < NB; i += KB_THREADS) lh[i] = 0;
    __syncthreads();

    const int base = blockIdx.x * KB_CHUNK + t * KB_EPT;
    int d[KB_EPT], rank[KB_EPT];
    const bool full = (base + KB_EPT - 1 < E);
    if (full) {
        int4 dv = *(const int4*)(dst + base);
        d[0] = dv.x; d[1] = dv.y; d[2] = dv.z; d[3] = dv.w;
#pragma unroll
        for (int i = 0; i < KB_EPT; i++)
            rank[i] = atomicAdd(&lh[d[i] >> BKT_SHIFT], 1);
    } else {
#pragma unroll
        for (int i = 0; i < KB_EPT; i++) {
            int e = base + i;
            if (e < E) {
                d[i] = dst[e];
                rank[i] = atomicAdd(&lh[d[i] >> BKT_SHIFT], 1);
            } else {
                d[i] = -1; rank[i] = 0;
            }
        }
    }
    __syncthreads();
    // reserve a contiguous range per touched bucket (global cursor)
    for (int i = t; i < NB; i += KB_THREADS) {
        int c = lh[i];
        lh[i] = c ? atomicAdd(&bcnt[i], c) : 0;
    }
    __syncthreads();
    if (full) {
        int4 sv = *(const int4*)(src + base);
        int s[KB_EPT] = {sv.x, sv.y, sv.z, sv.w};
#pragma unroll
        for (int i = 0; i < KB_EPT; i++) {
            int bkt = d[i] >> BKT_SHIFT;
            size_t pos = (size_t)bkt * BCAP + lh[bkt] + rank[i];
            bpack[pos] = ((uint32_t)s[i] << BKT_SHIFT) | (uint32_t)(d[i] & (BKT_W - 1));
        }
    } else {
#pragma unroll
        for (int i = 0; i < KB_EPT; i++) {
            if (d[i] >= 0) {
                int bkt = d[i] >> BKT_SHIFT;
                size_t pos = (size_t)bkt * BCAP + lh[bkt] + rank[i];
                bpack[pos] = ((uint32_t)src[base + i] << BKT_SHIFT) | (uint32_t)(d[i] & (BKT_W - 1));
            }
        }
    }
}

// ---------------- kC_csr: per-bucket CSR build, 4-padded segments, fixed-stride output ----------
// Node v's edges live in csr[offs[v] .. ends[v]) with ends-offs a multiple of 4; pad slots
// hold index n (zero row).  No global bucket scan needed (fixed stride).
__global__ __launch_bounds__(256) void kC_csr(const uint32_t* __restrict__ bpack,
                                              const int* __restrict__ bcnt, int NB, int n,
                                              float* __restrict__ dinv,
                                              int* __restrict__ offs,
                                              int* __restrict__ ends,
                                              int* __restrict__ csr) {
    __shared__ int pr[BKT_W];
    __shared__ int cnt[BKT_W];
    __shared__ int cur[BKT_W];
    __shared__ int pend[BKT_W];

    const int t = threadIdx.x;
    const int b = blockIdx.x;
    const int nb0 = b << BKT_SHIFT;
    const int wlen = min(BKT_W, n - nb0);
    const int cntb = bcnt[b];
    const uint32_t* bp = bpack + (size_t)b * BCAP;
    const int base = b * CSTRIDE;

    if (t < BKT_W) cnt[t] = 0;
    __syncthreads();
    for (int e = t; e < cntb; e += 256)
        atomicAdd(&cnt[bp[e] & (BKT_W - 1)], 1);
    __syncthreads();

    int v = (t < BKT_W) ? cnt[t] : 0;
    int pv = (v + 3) & ~3;                 // padded per-node length
    if (t < BKT_W) pr[t] = pv;
    __syncthreads();
    for (int off = 1; off < BKT_W; off <<= 1) {
        int x = (t >= off && t < BKT_W) ? pr[t - off] : 0;
        __syncthreads();
        if (t < BKT_W) pr[t] += x;
        __syncthreads();
    }
    if (t < BKT_W) {
        int st = base + pr[t] - pv;
        cur[t] = st;
        pend[t] = st + pv;
        if (t < wlen) {
            offs[nb0 + t] = st;
            ends[nb0 + t] = st + pv;
            dinv[nb0 + t] = rsqrtf((float)(v + 1));   // true count, not padded
        }
    }
    __syncthreads();

    for (int e = t; e < cntb; e += 256) {
        uint32_t p = bp[e];
        int pos = atomicAdd(&cur[p & (BKT_W - 1)], 1);
        csr[pos] = (int)(p >> BKT_SHIFT);
    }
    __syncthreads();
    // fill pad slots with sentinel (zero row); cur[t] == st+v after scatter
    if (t < BKT_W) {
        int qe = pend[t];
        for (int q = cur[t]; q < qe; q++) csr[q] = n;
    }
}

// ---------------- k_gemm1: layer-1 GEMM, f32 in (x), fp8 out (xw1), dinv-scaled ----------------
__global__ __launch_bounds__(256) void k_gemm1(const float* __restrict__ x,
                                               const ushort_t* __restrict__ Wt,
                                               const float* __restrict__ dinv,
                                               uint8_t* __restrict__ C, int n) {
    __shared__ ushort_t al[64 * 136];
    __shared__ ushort_t wl[128 * 136];
    const int t = threadIdx.x;
    const int l = t & 63;
    const int wave = t >> 6;
    const int lane15 = l & 15;
    const int quad = l >> 4;
    const int m0 = blockIdx.x * 64;
    const int rows = min(64, n - m0);

#pragma unroll
    for (int i = 0; i < 8; i++) {
        int f = t + 256 * i;
        int r = f >> 4, c = f & 15;
        *(uint4*)(&wl[r * 136 + c * 8]) = ((const uint4*)Wt)[f];
    }
    {
        const float4* Ap = (const float4*)(x + (size_t)m0 * 128);
        int nf = rows * 32;
#pragma unroll
        for (int i = 0; i < 8; i++) {
            int f = t + 256 * i;
            float4 vv = make_float4(0.f, 0.f, 0.f, 0.f);
            if (f < nf) vv = Ap[f];
            ushort4 us;
            us.x = f2bf(vv.x); us.y = f2bf(vv.y); us.z = f2bf(vv.z); us.w = f2bf(vv.w);
            int r = f >> 5, c = f & 31;
            *(ushort4*)(&al[r * 136 + c * 4]) = us;
        }
    }
    __syncthreads();

    f32x4 acc[8];
#pragma unroll
    for (int nt = 0; nt < 8; nt++) acc[nt] = (f32x4){0.f, 0.f, 0.f, 0.f};

    const int arow = wave * 16 + lane15;
#pragma unroll
    for (int kt = 0; kt < 4; kt++) {
        bf16x8 af = *(const bf16x8*)(&al[arow * 136 + kt * 32 + quad * 8]);
#pragma unroll
        for (int nt = 0; nt < 8; nt++) {
            bf16x8 bfr = *(const bf16x8*)(&wl[(nt * 16 + lane15) * 136 + kt * 32 + quad * 8]);
            acc[nt] = __builtin_amdgcn_mfma_f32_16x16x32_bf16(af, bfr, acc[nt], 0, 0, 0);
        }
    }

    const int rbase = m0 + wave * 16 + quad * 4;
    float dsc[4];
#pragma unroll
    for (int r = 0; r < 4; r++)
        dsc[r] = (rbase + r < n) ? dinv[rbase + r] : 0.f;
#pragma unroll
    for (int nt = 0; nt < 8; nt++) {
        int c0 = nt * 16 + lane15;
#pragma unroll
        for (int r = 0; r < 4; r += 2) {
            int pk = __builtin_amdgcn_cvt_pk_fp8_f32(acc[nt][r] * dsc[r],
                                                     acc[nt][r + 1] * dsc[r + 1], 0, false);
            int row0 = rbase + r, row1 = rbase + r + 1;
            if (row0 < n) C[(size_t)row0 * 128 + c0] = (uint8_t)pk;
            if (row1 < n) C[(size_t)row1 * 128 + c0] = (uint8_t)(pk >> 8);
        }
    }
}

// ---------------- MFMA GEMM (layer 2): bf16 in (h), fp8 out (xw2), dinv-scaled ----------------
__global__ __launch_bounds__(256) void k_gemm_mfma(const ushort_t* __restrict__ A,
                                                   const ushort_t* __restrict__ Wt,
                                                   const float* __restrict__ dinv,
                                                   uint8_t* __restrict__ C, int n) {
    __shared__ ushort_t al[64 * 136];
    __shared__ ushort_t wl[128 * 136];
    const int t = threadIdx.x;
    const int l = t & 63;
    const int wave = t >> 6;
    const int lane15 = l & 15;
    const int quad = l >> 4;
    const int m0 = blockIdx.x * 64;
    const int rows = min(64, n - m0);

#pragma unroll
    for (int i = 0; i < 8; i++) {
        int f = t + 256 * i;
        int r = f >> 4, c = f & 15;
        *(uint4*)(&wl[r * 136 + c * 8]) = ((const uint4*)Wt)[f];
    }
    {
        const uint4* Ap = (const uint4*)(A + (size_t)m0 * 128);
        int nf = rows * 16;
#pragma unroll
        for (int i = 0; i < 4; i++) {
            int f = t + 256 * i;
            uint4 v = make_uint4(0, 0, 0, 0);
            if (f < nf) v = Ap[f];
            int r = f >> 4, c = f & 15;
            *(uint4*)(&al[r * 136 + c * 8]) = v;
        }
    }
    __syncthreads();

    f32x4 acc[8];
#pragma unroll
    for (int nt = 0; nt < 8; nt++) acc[nt] = (f32x4){0.f, 0.f, 0.f, 0.f};

    const int arow = wave * 16 + lane15;
#pragma unroll
    for (int kt = 0; kt < 4; kt++) {
        bf16x8 af = *(const bf16x8*)(&al[arow * 136 + kt * 32 + quad * 8]);
#pragma unroll
        for (int nt = 0; nt < 8; nt++) {
            bf16x8 bfr = *(const bf16x8*)(&wl[(nt * 16 + lane15) * 136 + kt * 32 + quad * 8]);
            acc[nt] = __builtin_amdgcn_mfma_f32_16x16x32_bf16(af, bfr, acc[nt], 0, 0, 0);
        }
    }

    const int rbase = m0 + wave * 16 + quad * 4;
    float dsc[4];
#pragma unroll
    for (int r = 0; r < 4; r++)
        dsc[r] = (rbase + r < n) ? dinv[rbase + r] : 0.f;
#pragma unroll
    for (int nt = 0; nt < 8; nt++) {
        int c0 = nt * 16 + lane15;
#pragma unroll
        for (int r = 0; r < 4; r += 2) {
            int pk = __builtin_amdgcn_cvt_pk_fp8_f32(acc[nt][r] * dsc[r],
                                                     acc[nt][r + 1] * dsc[r + 1], 0, false);
            int row0 = rbase + r, row1 = rbase + r + 1;
            if (row0 < n) C[(size_t)row0 * 128 + c0] = (uint8_t)pk;
            if (row1 < n) C[(size_t)row1 * 128 + c0] = (uint8_t)(pk >> 8);
        }
    }
}

// ---------------- Aggregation: proven 16/8 geometry, int4 csr loads, exact 4-padded segments --
__global__ __launch_bounds__(256) void k_agg(const ushort_t* __restrict__ xw,   // fp8 pairs
                                             const int* __restrict__ offsets,
                                             const int* __restrict__ ends,
                                             const int* __restrict__ csr,
                                             const float* __restrict__ dinv,
                                             const float* __restrict__ bias,
                                             ushort_t* __restrict__ out, int n) {
    const int l = threadIdx.x & 63;
    const int wave = (blockIdx.x << 2) | (threadIdx.x >> 6);
    const int wstride = gridDim.x << 2;
    const float2 bb = ((const float2*)bias)[l];
    uint32_t* out32 = (uint32_t*)out;

    for (int v = wave; v < n; v += wstride) {
        uint32_t pv = (uint32_t)xw[(size_t)v * 64 + l];
        f32x2 fs = __builtin_amdgcn_cvt_pk_f32_fp8((int)pv, false);
        float ax = fs.x, ay = fs.y;

        int e  = __builtin_amdgcn_readfirstlane(offsets[v]);
        int e1 = __builtin_amdgcn_readfirstlane(ends[v]);

        for (; e + 15 < e1; e += 16) {
            const int4* c4 = (const int4*)(csr + e);
            int4 w0 = c4[0], w1 = c4[1], w2 = c4[2], w3 = c4[3];
            int u[16];
            u[0]  = __builtin_amdgcn_readfirstlane(w0.x);
            u[1]  = __builtin_amdgcn_readfirstlane(w0.y);
            u[2]  = __builtin_amdgcn_readfirstlane(w0.z);
            u[3]  = __builtin_amdgcn_readfirstlane(w0.w);
            u[4]  = __builtin_amdgcn_readfirstlane(w1.x);
            u[5]  = __builtin_amdgcn_readfirstlane(w1.y);
            u[6]  = __builtin_amdgcn_readfirstlane(w1.z);
            u[7]  = __builtin_amdgcn_readfirstlane(w1.w);
            u[8]  = __builtin_amdgcn_readfirstlane(w2.x);
            u[9]  = __builtin_amdgcn_readfirstlane(w2.y);
            u[10] = __builtin_amdgcn_readfirstlane(w2.z);
            u[11] = __builtin_amdgcn_readfirstlane(w2.w);
            u[12] = __builtin_amdgcn_readfirstlane(w3.x);
            u[13] = __builtin_amdgcn_readfirstlane(w3.y);
            u[14] = __builtin_amdgcn_readfirstlane(w3.z);
            u[15] = __builtin_amdgcn_readfirstlane(w3.w);
            uint32_t p[16];
#pragma unroll
            for (int i = 0; i < 16; i++) p[i] = (uint32_t)xw[(size_t)u[i] * 64 + l];
#pragma unroll
            for (int i = 0; i < 16; i++) {
                f32x2 f = __builtin_amdgcn_cvt_pk_f32_fp8((int)p[i], false);
                ax += f.x; ay += f.y;
            }
        }
        for (; e + 7 < e1; e += 8) {
            const int4* c4 = (const int4*)(csr + e);
            int4 w0 = c4[0], w1 = c4[1];
            int u[8];
            u[0] = __builtin_amdgcn_readfirstlane(w0.x);
            u[1] = __builtin_amdgcn_readfirstlane(w0.y);
            u[2] = __builtin_amdgcn_readfirstlane(w0.z);
            u[3] = __builtin_amdgcn_readfirstlane(w0.w);
            u[4] = __builtin_amdgcn_readfirstlane(w1.x);
            u[5] = __builtin_amdgcn_readfirstlane(w1.y);
            u[6] = __builtin_amdgcn_readfirstlane(w1.z);
            u[7] = __builtin_amdgcn_readfirstlane(w1.w);
            uint32_t p[8];
#pragma unroll
            for (int i = 0; i < 8; i++) p[i] = (uint32_t)xw[(size_t)u[i] * 64 + l];
#pragma unroll
            for (int i = 0; i < 8; i++) {
                f32x2 f = __builtin_amdgcn_cvt_pk_f32_fp8((int)p[i], false);
                ax += f.x; ay += f.y;
            }
        }
        for (; e + 3 < e1; e += 4) {
            int4 w0 = *(const int4*)(csr + e);
            int u[4];
            u[0] = __builtin_amdgcn_readfirstlane(w0.x);
            u[1] = __builtin_amdgcn_readfirstlane(w0.y);
            u[2] = __builtin_amdgcn_readfirstlane(w0.z);
            u[3] = __builtin_amdgcn_readfirstlane(w0.w);
            uint32_t p[4];
#pragma unroll
            for (int i = 0; i < 4; i++) p[i] = (uint32_t)xw[(size_t)u[i] * 64 + l];
#pragma unroll
            for (int i = 0; i < 4; i++) {
                f32x2 f = __builtin_amdgcn_cvt_pk_f32_fp8((int)p[i], false);
                ax += f.x; ay += f.y;
            }
        }

        float dv = dinv[v];
        float ox = fmaxf(fmaf(ax, dv, bb.x), 0.f);
        float oy = fmaxf(fmaf(ay, dv, bb.y), 0.f);
        out32[(size_t)v * 64 + l] = ((uint32_t)f2bf(oy) << 16) | (uint32_t)f2bf(ox);
    }
}

// ---------------- Fused mean-pool + FC (separate 256-block kernel; proven) ----------------
__global__ __launch_bounds__(256) void k_poolfc(const ushort_t* __restrict__ h,
                                                float* __restrict__ pooled, int n,
                                                const float* __restrict__ Wfc,
                                                const float* __restrict__ bfc,
                                                float* __restrict__ out, float invN,
                                                int* __restrict__ counter) {
    __shared__ float red[512];
    __shared__ int lastFlag;
    __shared__ float pl[128];
    const int t = threadIdx.x;
    const int l = t & 63;
    const int wv = (blockIdx.x << 2) | (t >> 6);
    const int ws = gridDim.x << 2;
    const uint32_t* h32 = (const uint32_t*)h;

    const int span = (n + ws - 1) / ws;
    int r0 = wv * span;
    int r1 = min(n, r0 + span);
    float sx = 0.f, sy = 0.f;
    int r = r0;
    for (; r + 3 < r1; r += 4) {
        uint32_t p0 = h32[(size_t)r * 64 + l];
        uint32_t p1 = h32[(size_t)(r + 1) * 64 + l];
        uint32_t p2 = h32[(size_t)(r + 2) * 64 + l];
        uint32_t p3 = h32[(size_t)(r + 3) * 64 + l];
        sx += bf_lo(p0) + bf_lo(p1) + bf_lo(p2) + bf_lo(p3);
        sy += bf_hi(p0) + bf_hi(p1) + bf_hi(p2) + bf_hi(p3);
    }
    for (; r < r1; r++) {
        uint32_t p = h32[(size_t)r * 64 + l];
        sx += bf_lo(p); sy += bf_hi(p);
    }
    red[t] = sx;
    red[256 + t] = sy;
    __syncthreads();
    float* slice = pooled + (blockIdx.x & (PSLICES - 1)) * 128;
    if (t < 64) {
        sx = red[t] + red[t + 64] + red[t + 128] + red[t + 192];
        sy = red[256 + t] + red[256 + t + 64] + red[256 + t + 128] + red[256 + t + 192];
        atomicAdd(&slice[2 * l], sx);
        atomicAdd(&slice[2 * l + 1], sy);
    }
    __threadfence();
    __syncthreads();
    if (t == 0) {
        int old = atomicAdd(counter, 1);
        lastFlag = (old == (int)gridDim.x - 1);
    }
    __syncthreads();
    if (lastFlag) {
        if (t < 128) {
            float acc = 0.f;
#pragma unroll
            for (int s = 0; s < PSLICES; s++)
                acc += atomicAdd(&pooled[s * 128 + t], 0.f);   // coherent read
            pl[t] = acc;
        }
        __syncthreads();
        if (t < 128) {
            float acc = bfc[t];
#pragma unroll 8
            for (int k = 0; k < 128; k++)
                acc = fmaf(pl[k] * invN, Wfc[k * 128 + t], acc);
            out[t] = acc;
        }
    }
}

// ---------------- launcher ----------------
extern "C" void kernel_launch(void* const* d_in, const int* in_sizes, int n_in,
                              void* d_out, int out_size, void* d_ws, size_t ws_size,
                              hipStream_t stream) {
    const float* x    = (const float*)d_in[0];
    const int*   ei   = (const int*)d_in[1];
    const float* W1   = (const float*)d_in[2];
    const float* b1   = (const float*)d_in[3];
    const float* W2   = (const float*)d_in[4];
    const float* b2   = (const float*)d_in[5];
    const float* Wfc  = (const float*)d_in[6];
    const float* bfc  = (const float*)d_in[7];
    float*       out  = (float*)d_out;

    const int n = in_sizes[0] / 128;
    const int E = in_sizes[1] / 2;
    const int* src = ei;
    const int* dst = ei + E;
    const int NB = (n + BKT_W - 1) >> BKT_SHIFT;   // 782

    char* w = (char*)d_ws;
    uint8_t*  xwq = (uint8_t*)w;  w += (size_t)(n + 1) * 128;           // fp8 [n+1][128], row n = zeros
    ushort_t* h   = (ushort_t*)w; w += (size_t)n * 128 * sizeof(ushort_t);
    int*      csr = (int*)w;      w += (size_t)NB * CSTRIDE * sizeof(int);
    uint32_t* bpack = (uint32_t*)w; w += (size_t)NB * BCAP * sizeof(uint32_t);
    float* dinv = (float*)w;  w += (size_t)n * sizeof(float);
    int*   offs = (int*)w;    w += (size_t)n * sizeof(int);
    int*   ends = (int*)w;    w += (size_t)n * sizeof(int);
    w = (char*)(((uintptr_t)w + 127) & ~(uintptr_t)127);
    int*   bcnt  = (int*)w;   w += NB_MAX * sizeof(int);
    int*   counter = (int*)w; w += 32 * sizeof(int);
    float* pooled = (float*)w; w += PSLICES * 128 * sizeof(float);
    ushort_t* Wt1 = (ushort_t*)w; w += 16384 * sizeof(ushort_t);
    ushort_t* Wt2 = (ushort_t*)w; w += 16384 * sizeof(ushort_t);

    const int ntiles64 = (n + 63) / 64;
    const float invN = 1.0f / (float)n;

    kW_init<<<65, 256, 0, stream>>>(W1, W2, Wt1, Wt2, bcnt, pooled, counter, xwq, n);
    kB_bucket<<<(E + KB_CHUNK - 1) / KB_CHUNK, KB_THREADS, 0, stream>>>(src, dst, E, NB, bcnt, bpack);
    kC_csr<<<NB, 256, 0, stream>>>(bpack, bcnt, NB, n, dinv, offs, ends, csr);
    k_gemm1<<<ntiles64, 256, 0, stream>>>(x, Wt1, dinv, xwq, n);

    k_agg<<<8192, 256, 0, stream>>>((const ushort_t*)xwq, offs, ends, csr, dinv, b1, h, n);
    k_gemm_mfma<<<ntiles64, 256, 0, stream>>>(h, Wt2, dinv, xwq, n);
    k_agg<<<8192, 256, 0, stream>>>((const ushort_t*)xwq, offs, ends, csr, dinv, b2, h, n);

    k_poolfc<<<256, 256, 0, stream>>>(h, pooled, n, Wfc, bfc, out, invN, counter);
}